// Round 15
// baseline (967.464 us; speedup 1.0000x reference)
//
#include <hip/hip_runtime.h>
#include <hip/hip_fp16.h>
#include <math.h>

#define N_NODES 50000
#define N_EDGES 800000
#define EP (N_EDGES + N_NODES)   /* 850000 with self loops */
#define IN_CH 128
#define HID 64
#define HEADS 4
#define F1 (HEADS * HID)         /* 256 */
#define LAT 32
#define NEG 0.2f
#define CAP 64                    /* bucket capacity per dst; P(overflow) ~1e-13 */
#define NW (512 * 128 + 64 * 256) /* weight elements: 81920 */
#define G1B ((N_NODES + 31) / 32)    /* 1563 gemm1 blocks */
#define NSCAN 64                     /* owner-scan blocks (bucket build) */
#define DPB 782                      /* dsts per scan block: 64*782 = 50048 */
#define TB (NSCAN + G1B)             /* 1627 fused-grid blocks */

typedef __attribute__((ext_vector_type(8))) short short8;
typedef __attribute__((ext_vector_type(8))) unsigned short ushort8v;
typedef __attribute__((ext_vector_type(4))) float f32x4;
typedef __attribute__((ext_vector_type(2))) float f32x2;
typedef __attribute__((ext_vector_type(4))) unsigned int uint4v;

__device__ __forceinline__ unsigned short f2bf(float f) {
    unsigned int x = __float_as_uint(f);
    x += 0x7fffu + ((x >> 16) & 1u);       // round-to-nearest-even
    return (unsigned short)(x >> 16);
}
__device__ __forceinline__ float bf2f(unsigned short u) {
    return __uint_as_float(((unsigned int)u) << 16);
}
__device__ __forceinline__ float h2f(unsigned short u) {
    return __half2float(__ushort_as_half(u));
}
// unpack 2 bf16 (packed in a u32) -> float2; 2 VALU (lshl, and)
__device__ __forceinline__ f32x2 up2(unsigned w) {
    f32x2 r;
    r[0] = __uint_as_float(w << 16);
    r[1] = __uint_as_float(w & 0xffff0000u);
    return r;
}
__device__ __forceinline__ f32x4 mfma_bf16(short8 a, short8 b, f32x4 c) {
    return __builtin_amdgcn_mfma_f32_16x16x32_bf16(a, b, c, 0, 0, 0);
}
// packed f32->bf16 RNE: 1 instr per 2 floats (vs ~6 for the bit-hack pair)
__device__ __forceinline__ unsigned cvt_pk_bf16(float lo, float hi) {
    unsigned r;
    asm("v_cvt_pk_bf16_f32 %0, %1, %2" : "=v"(r) : "v"(lo), "v"(hi));
    return r;
}
__device__ __forceinline__ short8 pack_bf16x8(float4 A, float4 B) {
    uint4v u;
    u[0] = cvt_pk_bf16(A.x, A.y);
    u[1] = cvt_pk_bf16(A.z, A.w);
    u[2] = cvt_pk_bf16(B.x, B.y);
    u[3] = cvt_pk_bf16(B.z, B.w);
    return __builtin_bit_cast(short8, u);
}

// -------- dispatch 1: weight transpose+convert (no zeroing needed anymore) ----
__global__ void conv_w(const float* __restrict__ Wl1, const float* __restrict__ Wr1,
                       const float* __restrict__ Wl2, const float* __restrict__ Wr2,
                       unsigned short* __restrict__ Wt1, unsigned short* __restrict__ Wt2) {
    int idx = blockIdx.x * 256 + threadIdx.x;
    if (idx < 512 * 128) {
        int n = idx >> 7, k = idx & 127;
        float v = (n < 256) ? Wl1[(size_t)k * 256 + n] : Wr1[(size_t)k * 256 + (n - 256)];
        Wt1[idx] = f2bf(v);
    } else if (idx < NW) {
        int j = idx - 512 * 128;
        int n = j >> 8, k = j & 255;
        float v = (n < 32) ? Wl2[(size_t)k * 32 + n] : Wr2[(size_t)k * 32 + (n - 32)];
        Wt2[j] = f2bf(v);
    }
}

// ---- FUSED dispatch 2: GEMM1 (MFMA) + owner-scan bucket build ----
// r10/r14 nulls + occupancy-invariance pinned scatter's 60us on the returning
// global atomicAdd itself (~14 G/s wall). Owner-computes scan removes ALL
// global atomics: 64 blocks each own 782 dsts, count in LDS (ds_add_rtn),
// stream the L2-resident dst array, write srcsP into their own 100KB region.
// Scan ~20us on 64 CUs hides under the 1563 gemm blocks on the rest.
__global__ __launch_bounds__(256) void gemm1_scan(const float* __restrict__ x,
                                                  const unsigned short* __restrict__ Wt1,
                                                  unsigned short* __restrict__ xlh,
                                                  unsigned short* __restrict__ xrh,
                                                  const int* __restrict__ ei,
                                                  int* __restrict__ cnt,
                                                  unsigned short* __restrict__ srcsP) {
    __shared__ int lcnt[DPB];
    int bid = blockIdx.x;
    if (bid < NSCAN) {
        int d0 = bid * DPB;
        for (int i = threadIdx.x; i < DPB; i += 256) lcnt[i] = 0;
        __syncthreads();
        long e = threadIdx.x;
        for (; e + 768 < N_EDGES; e += 1024) {
            int dv0 = ei[N_EDGES + e];
            int dv1 = ei[N_EDGES + e + 256];
            int dv2 = ei[N_EDGES + e + 512];
            int dv3 = ei[N_EDGES + e + 768];
            unsigned r0 = (unsigned)(dv0 - d0);
            if (r0 < DPB) {
                int pos = atomicAdd(&lcnt[r0], 1);
                if (pos < CAP)
                    __builtin_nontemporal_store((unsigned short)ei[e],
                                                &srcsP[(dv0 << 6) + pos]);
            }
            unsigned r1 = (unsigned)(dv1 - d0);
            if (r1 < DPB) {
                int pos = atomicAdd(&lcnt[r1], 1);
                if (pos < CAP)
                    __builtin_nontemporal_store((unsigned short)ei[e + 256],
                                                &srcsP[(dv1 << 6) + pos]);
            }
            unsigned r2 = (unsigned)(dv2 - d0);
            if (r2 < DPB) {
                int pos = atomicAdd(&lcnt[r2], 1);
                if (pos < CAP)
                    __builtin_nontemporal_store((unsigned short)ei[e + 512],
                                                &srcsP[(dv2 << 6) + pos]);
            }
            unsigned r3 = (unsigned)(dv3 - d0);
            if (r3 < DPB) {
                int pos = atomicAdd(&lcnt[r3], 1);
                if (pos < CAP)
                    __builtin_nontemporal_store((unsigned short)ei[e + 768],
                                                &srcsP[(dv3 << 6) + pos]);
            }
        }
        for (; e < N_EDGES; e += 256) {
            int dv = ei[N_EDGES + e];
            unsigned r = (unsigned)(dv - d0);
            if (r < DPB) {
                int pos = atomicAdd(&lcnt[r], 1);
                if (pos < CAP)
                    __builtin_nontemporal_store((unsigned short)ei[e],
                                                &srcsP[(dv << 6) + pos]);
            }
        }
        __syncthreads();
        // append self-loop (one per dst) + write final counts
        for (int i = threadIdx.x; i < DPB; i += 256) {
            int d = d0 + i;
            if (d < N_NODES) {
                int pos = lcnt[i];
                if (pos < CAP)
                    __builtin_nontemporal_store((unsigned short)d, &srcsP[(d << 6) + pos]);
                cnt[d] = pos + 1;
            }
        }
        return;
    }
    int wid = bid - NSCAN;               // gemm block id in [0, G1B)

    // ---- gemm1 body (x->bf16 via v_cvt_pk_bf16_f32; D[feature][node]) ----
    int wave = threadIdx.x >> 6;
    int lane = threadIdx.x & 63;
    int quad = lane >> 4, lo = lane & 15;
    int row0 = wid * 32;
    int colw = wave * 128;
    int rB0 = min(row0 + lo, N_NODES - 1);
    int rB1 = min(row0 + 16 + lo, N_NODES - 1);
    f32x4 acc[2][8];
#pragma unroll
    for (int rt = 0; rt < 2; rt++)
#pragma unroll
        for (int ct = 0; ct < 8; ct++) acc[rt][ct] = (f32x4){0.f, 0.f, 0.f, 0.f};
#pragma unroll
    for (int ks = 0; ks < 4; ks++) {
        int koff = ks * 32 + quad * 8;
        float4 fa0 = *(const float4*)(x + (size_t)rB0 * IN_CH + koff);
        float4 fb0 = *(const float4*)(x + (size_t)rB0 * IN_CH + koff + 4);
        float4 fa1 = *(const float4*)(x + (size_t)rB1 * IN_CH + koff);
        float4 fb1 = *(const float4*)(x + (size_t)rB1 * IN_CH + koff + 4);
        short8 b0 = pack_bf16x8(fa0, fb0);
        short8 b1 = pack_bf16x8(fa1, fb1);
#pragma unroll
        for (int ct = 0; ct < 8; ct++) {
            short8 a = *(const short8*)(Wt1 + (size_t)(colw + ct * 16 + lo) * IN_CH + koff);
            acc[0][ct] = mfma_bf16(a, b0, acc[0][ct]);
            acc[1][ct] = mfma_bf16(a, b1, acc[1][ct]);
        }
    }
#pragma unroll
    for (int rt = 0; rt < 2; rt++) {
        int node = row0 + rt * 16 + lo;
        if (node < N_NODES) {
#pragma unroll
            for (int ct = 0; ct < 8; ct++) {
                int feat = colw + ct * 16 + quad * 4;
                uint2 u;
                u.x = cvt_pk_bf16(acc[rt][ct][0], acc[rt][ct][1]);
                u.y = cvt_pk_bf16(acc[rt][ct][2], acc[rt][ct][3]);
                if (feat < F1)
                    *(uint2*)(xlh + (size_t)node * F1 + feat) = u;
                else
                    *(uint2*)(xrh + (size_t)node * F1 + (feat - F1)) = u;
            }
        }
    }
}

// ------- fused L1: per-dst softmax aggregation + bias + ELU -> hbf (bf16) -------
// Packed-f32 inner loop (r13; numerics = f32 algebra).
__global__ __launch_bounds__(256) void fused_l1(const unsigned short* __restrict__ xlh,
                                                const unsigned short* __restrict__ xrh,
                                                unsigned short* __restrict__ hbf,
                                                const unsigned short* __restrict__ srcsP,
                                                const int* __restrict__ cnt,
                                                const float* __restrict__ att,
                                                const float* __restrict__ bias) {
    int wave = threadIdx.x >> 6;
    int lane = threadIdx.x & 63;
    int h = lane >> 5;                  // edge parity
    int c = lane & 31;                  // channel-lane: ch c*8 .. c*8+7 (head = c>>3)
    int c0 = c << 3;
    int d = blockIdx.x * 4 + wave;
    if (d >= N_NODES) return;
    uint4v xru = *(const uint4v*)(xrh + (size_t)d * F1 + c0);
    float4 atA = *(const float4*)(att + c0);
    float4 atB = *(const float4*)(att + c0 + 4);
    f32x2 xr2v[4], at2[4];
#pragma unroll
    for (int p = 0; p < 4; p++) xr2v[p] = up2(xru[p]);
    at2[0] = (f32x2){atA.x, atA.y};
    at2[1] = (f32x2){atA.z, atA.w};
    at2[2] = (f32x2){atB.x, atB.y};
    at2[3] = (f32x2){atB.z, atB.w};
    const f32x2 negv = (f32x2){NEG, NEG};
    int start = d << 6;
    int dg    = min(CAP, __builtin_amdgcn_readfirstlane(cnt[d]));
    float l = 0.f;
    f32x2 acc2[4] = {};
    int jj = h;                          // this half's edges: h, h+2, h+4, ...
    int s = srcsP[start + jj];
    uint4v raw = *(const uint4v*)(xlh + (size_t)s * F1 + c0);
    int sN = srcsP[start + jj + 2];
    int iters = (dg + 1) >> 1;
    for (int k = 0; k < iters; k++) {
        uint4v cr = raw;
        raw = *(const uint4v*)(xlh + (size_t)sN * F1 + c0);
        sN = srcsP[start + jj + 4];
        f32x2 ap[4];
        f32x2 sp = (f32x2){0.f, 0.f};
#pragma unroll
        for (int p = 0; p < 4; p++) {
            ap[p] = up2(cr[p]);
            f32x2 v = ap[p] + xr2v[p];                       // v_pk_add_f32
            f32x2 lk = __builtin_elementwise_max(v, v * negv); // pk_mul + pk_max
            sp = lk * at2[p] + sp;                           // v_pk_fma_f32
        }
        float sc = sp[0] + sp[1];
        sc += __shfl_xor(sc, 1);
        sc += __shfl_xor(sc, 2);
        sc += __shfl_xor(sc, 4);
        float ex = (jj < dg) ? __expf(sc) : 0.f;
        l += ex;
        f32x2 ex2 = (f32x2){ex, ex};
#pragma unroll
        for (int p = 0; p < 4; p++) acc2[p] = ex2 * ap[p] + acc2[p]; // pk_fma
        jj += 2;
    }
    float acc[8];
#pragma unroll
    for (int p = 0; p < 4; p++) { acc[2 * p] = acc2[p][0]; acc[2 * p + 1] = acc2[p][1]; }
    l += __shfl_xor(l, 32);
#pragma unroll
    for (int i = 0; i < 8; i++) acc[i] += __shfl_xor(acc[i], 32);
    if (h == 0) {
        float inv = 1.0f / l;
        float4 bA = *(const float4*)(bias + c0);
        float4 bB = *(const float4*)(bias + c0 + 4);
        float b8[8] = {bA.x, bA.y, bA.z, bA.w, bB.x, bB.y, bB.z, bB.w};
        ushort8v ho;
#pragma unroll
        for (int i = 0; i < 8; i++) {
            float o = acc[i] * inv + b8[i];
            o = o > 0.f ? o : __expf(o) - 1.0f;
            ho[i] = (unsigned short)f2bf(o);
        }
        *(ushort8v*)(hbf + (size_t)d * F1 + c0) = ho;
    }
}

// ---- GEMM2 (MFMA, swapped operands): hbf(N,256) @ Wt2^T -> xl2h fp16 / xr2 fp32 ----
__global__ __launch_bounds__(256) void gemm2_mfma(const unsigned short* __restrict__ hbf,
                                                  const unsigned short* __restrict__ Wt2,
                                                  __half* __restrict__ xl2h,
                                                  float* __restrict__ xr2) {
    int wave = threadIdx.x >> 6;
    int lane = threadIdx.x & 63;
    int quad = lane >> 4, lo = lane & 15;
    int row0 = blockIdx.x * 64 + wave * 16;
    int rB = min(row0 + lo, N_NODES - 1);
    f32x4 acc[4];
#pragma unroll
    for (int ct = 0; ct < 4; ct++) acc[ct] = (f32x4){0.f, 0.f, 0.f, 0.f};
#pragma unroll
    for (int ks = 0; ks < 8; ks++) {
        int koff = ks * 32 + quad * 8;
        short8 b = *(const short8*)(hbf + (size_t)rB * F1 + koff);
#pragma unroll
        for (int ct = 0; ct < 4; ct++) {
            short8 a = *(const short8*)(Wt2 + (size_t)(ct * 16 + lo) * F1 + koff);
            acc[ct] = mfma_bf16(a, b, acc[ct]);
        }
    }
    int node = row0 + lo;
    if (node < N_NODES) {
#pragma unroll
        for (int ct = 0; ct < 4; ct++) {
            int feat = ct * 16 + quad * 4;
            if (feat < LAT) {
                ushort4 u;
                u.x = __half_as_ushort(__float2half_rn(acc[ct][0]));
                u.y = __half_as_ushort(__float2half_rn(acc[ct][1]));
                u.z = __half_as_ushort(__float2half_rn(acc[ct][2]));
                u.w = __half_as_ushort(__float2half_rn(acc[ct][3]));
                *(ushort4*)((unsigned short*)xl2h + (size_t)node * LAT + feat) = u;
            } else {
                float4 f = make_float4(acc[ct][0], acc[ct][1], acc[ct][2], acc[ct][3]);
                *(float4*)(xr2 + (size_t)node * LAT + (feat - LAT)) = f;
            }
        }
    }
}

// ------- fused L2: one dst per wave; quarter-wave per edge, bucket layout -------
__global__ __launch_bounds__(256) void fused_l2(const __half* __restrict__ xl2h,
                                                const float* __restrict__ xr2,
                                                const unsigned short* __restrict__ srcsP,
                                                const int* __restrict__ cnt,
                                                const float* __restrict__ att,
                                                const float* __restrict__ bias,
                                                __half* __restrict__ zh) {
    int wave = threadIdx.x >> 6;
    int lane = threadIdx.x & 63;
    int q = lane >> 4;                  // edge parity class 0..3
    int c = lane & 15;                  // channel-lane: ch 2c, 2c+1
    int c2 = c << 1;
    int d = blockIdx.x * 4 + wave;
    if (d >= N_NODES) return;
    float xr0 = xr2[(size_t)d * LAT + c2];
    float xr1v = xr2[(size_t)d * LAT + c2 + 1];
    float av0 = att[c2], av1 = att[c2 + 1];
    float a60 = 0.6f * av0, a40 = 0.4f * av0;
    float a61 = 0.6f * av1, a41 = 0.4f * av1;
    int start = d << 6;
    int dg    = min(CAP, __builtin_amdgcn_readfirstlane(cnt[d]));
    float l = 0.f, acc0 = 0.f, acc1 = 0.f;
    int jj = q;                         // this quarter's edges: q, q+4, q+8, ...
    int s = srcsP[start + jj];
    __half2 raw = *(const __half2*)(xl2h + (size_t)s * LAT + c2);
    int sN = srcsP[start + jj + 4];
    int iters = (dg + 3) >> 2;
    for (int k = 0; k < iters; k++) {
        __half2 cr = raw;
        raw = *(const __half2*)(xl2h + (size_t)sN * LAT + c2);
        sN = srcsP[start + jj + 8];
        float a0 = __half2float(cr.x), a1 = __half2float(cr.y);
        float v0 = a0 + xr0;
        float v1 = a1 + xr1v;
        float sc = 0.f;
        sc = fmaf(v0, a60, sc);
        sc = fmaf(fabsf(v0), a40, sc);
        sc = fmaf(v1, a61, sc);
        sc = fmaf(fabsf(v1), a41, sc);
        sc += __shfl_xor(sc, 1);
        sc += __shfl_xor(sc, 2);
        sc += __shfl_xor(sc, 4);
        sc += __shfl_xor(sc, 8);
        float ex = (jj < dg) ? __expf(sc) : 0.f;
        l += ex;
        acc0 = fmaf(ex, a0, acc0);
        acc1 = fmaf(ex, a1, acc1);
        jj += 4;
    }
    l += __shfl_xor(l, 16); acc0 += __shfl_xor(acc0, 16); acc1 += __shfl_xor(acc1, 16);
    l += __shfl_xor(l, 32); acc0 += __shfl_xor(acc0, 32); acc1 += __shfl_xor(acc1, 32);
    if (q == 0) {
        __half2 o;
        o.x = __float2half_rn(acc0 / l + bias[c2]);
        o.y = __float2half_rn(acc1 / l + bias[c2 + 1]);
        *(__half2*)(zh + (size_t)d * LAT + c2) = o;
    }
}

// ------- decode: sigmoid(<z[row], z[col]>), z fp16, 4 lanes/edge, 16B loads ----
__global__ __launch_bounds__(256) void decode(const __half* __restrict__ zh,
                                              const int* __restrict__ ei,
                                              float* __restrict__ out) {
    int g = threadIdx.x >> 2;             // 64 edge-groups per block
    int lane = threadIdx.x & 3;
    long e = (long)blockIdx.x * 64 + g;
    if (e >= N_EDGES) return;
    int r = ei[e], c = ei[N_EDGES + e];
    int cc = lane << 3;                   // 8 channels
    ushort8v ur = *(const ushort8v*)((const unsigned short*)zh + (size_t)r * LAT + cc);
    ushort8v uc = *(const ushort8v*)((const unsigned short*)zh + (size_t)c * LAT + cc);
    float v = 0.f;
#pragma unroll
    for (int i = 0; i < 8; i++) {
        v += h2f(ur[i]) * h2f(uc[i]);
    }
    v += __shfl_xor(v, 1);
    v += __shfl_xor(v, 2);
    if (lane == 0) out[e] = 1.0f / (1.0f + __expf(-v));
}

extern "C" void kernel_launch(void* const* d_in, const int* in_sizes, int n_in,
                              void* d_out, int out_size, void* d_ws, size_t ws_size,
                              hipStream_t stream) {
    const float* x    = (const float*)d_in[0];
    const int*   ei   = (const int*)d_in[1];
    const float* Wl1  = (const float*)d_in[2];
    const float* Wr1  = (const float*)d_in[3];
    const float* att1 = (const float*)d_in[4];
    const float* b1   = (const float*)d_in[5];
    const float* Wl2  = (const float*)d_in[6];
    const float* Wr2  = (const float*)d_in[7];
    const float* att2 = (const float*)d_in[8];
    const float* b2   = (const float*)d_in[9];
    float* out = (float*)d_out;

    unsigned short* xrh = (unsigned short*)d_ws;                 // N*256 bf16 (25.6 MB)
    unsigned short* hbf = xrh + (size_t)N_NODES * F1;            // N*256 bf16 (25.6 MB)
    unsigned short* xlh = hbf + (size_t)N_NODES * F1;            // N*256 bf16 (25.6 MB)
    int* cnt = (int*)(xlh + (size_t)N_NODES * F1);               // N ints (16B-aligned)
    unsigned short* srcsP = (unsigned short*)(cnt + N_NODES);    // N*64+16 ushorts (6.4 MB)
    unsigned short* Wt1 = srcsP + (size_t)N_NODES * CAP + 16;    // 512*128 bf16
    unsigned short* Wt2 = Wt1 + 512 * 128;                       // 64*256 bf16
    // layer-2 buffers reuse the xlh region (dead after fused_l1): 12.8 MB
    __half* xl2h = (__half*)xlh;                                 // N*32 fp16
    float*  xr2  = (float*)(xl2h + (size_t)N_NODES * LAT);
    __half* zh   = (__half*)(xr2 + (size_t)N_NODES * LAT);

    // ---- 1: weights bf16 (no zeroing: scan writes all cnt entries) ----
    conv_w<<<(NW + 255) / 256, 256, 0, stream>>>(Wl1, Wr1, Wl2, Wr2, Wt1, Wt2);

    // ---- 2: FUSED layer-1 GEMM + owner-scan bucket build (0 global atomics) ----
    gemm1_scan<<<TB, 256, 0, stream>>>(x, Wt1, xlh, xrh, ei, cnt, srcsP);

    // ---- 3: layer 1 aggregate (packed-f32 math) ----
    fused_l1<<<(N_NODES + 3) / 4, 256, 0, stream>>>(xlh, xrh, hbf, srcsP, cnt, att1, b1);

    // ---- 4/5: layer 2 ----
    gemm2_mfma<<<(N_NODES + 63) / 64, 256, 0, stream>>>(hbf, Wt2, xl2h, xr2);
    fused_l2<<<(N_NODES + 3) / 4, 256, 0, stream>>>(xl2h, xr2, srcsP, cnt, att2, b2, zh);

    // ---- 6: decode ----
    decode<<<(N_EDGES + 63) / 64, 256, 0, stream>>>(zh, ei, out);
}

// Round 16
// 287.592 us; speedup vs baseline: 3.3640x; 3.3640x over previous
//
#include <hip/hip_runtime.h>
#include <hip/hip_fp16.h>
#include <math.h>

#define N_NODES 50000
#define N_EDGES 800000
#define IN_CH 128
#define HID 64
#define HEADS 4
#define F1 (HEADS * HID)         /* 256 */
#define LAT 32
#define NEG 0.2f
#define CAP 64                    /* bucket capacity per dst; P(overflow) ~1e-13 */
#define NW (512 * 128 + 64 * 256) /* weight elements: 81920 */
#define G1B ((N_NODES + 31) / 32)       /* 1563 gemm1 blocks */
#define SEB ((N_EDGES + 1023) / 1024)   /* 782 scatter blocks (4 edges/thread) */
#define TB (3 * SEB)                    /* 2346 fused-grid slots (2 gemm : 1 scatter) */

typedef __attribute__((ext_vector_type(8))) short short8;
typedef __attribute__((ext_vector_type(8))) unsigned short ushort8v;
typedef __attribute__((ext_vector_type(4))) float f32x4;
typedef __attribute__((ext_vector_type(2))) float f32x2;
typedef __attribute__((ext_vector_type(2))) unsigned int uint2v;
typedef __attribute__((ext_vector_type(4))) unsigned int uint4v;

__device__ __forceinline__ unsigned short f2bf(float f) {
    unsigned int x = __float_as_uint(f);
    x += 0x7fffu + ((x >> 16) & 1u);       // round-to-nearest-even
    return (unsigned short)(x >> 16);
}
__device__ __forceinline__ float bf2f(unsigned short u) {
    return __uint_as_float(((unsigned int)u) << 16);
}
__device__ __forceinline__ float h2f(unsigned short u) {
    return __half2float(__ushort_as_half(u));
}
// unpack 2 bf16 (packed in a u32) -> float2; 2 VALU (lshl, and)
__device__ __forceinline__ f32x2 up2(unsigned w) {
    f32x2 r;
    r[0] = __uint_as_float(w << 16);
    r[1] = __uint_as_float(w & 0xffff0000u);
    return r;
}
// REAL packed f32 (VOP3P, gfx90a+). r13's float2 '+'/'*' was a null ->
// clang likely scalarized; force the packed ops via inline asm.
__device__ __forceinline__ f32x2 pk_add(f32x2 a, f32x2 b) {
    f32x2 d;
    asm("v_pk_add_f32 %0, %1, %2" : "=v"(d) : "v"(a), "v"(b));
    return d;
}
__device__ __forceinline__ f32x2 pk_fma(f32x2 a, f32x2 b, f32x2 c) {
    f32x2 d;
    asm("v_pk_fma_f32 %0, %1, %2, %3" : "=v"(d) : "v"(a), "v"(b), "v"(c));
    return d;
}
__device__ __forceinline__ f32x2 abs2(f32x2 a) {
    uint2v u = __builtin_bit_cast(uint2v, a);
    u[0] &= 0x7fffffffu;
    u[1] &= 0x7fffffffu;
    return __builtin_bit_cast(f32x2, u);
}
__device__ __forceinline__ f32x4 mfma_bf16(short8 a, short8 b, f32x4 c) {
    return __builtin_amdgcn_mfma_f32_16x16x32_bf16(a, b, c, 0, 0, 0);
}
// packed f32->bf16 RNE: 1 instr per 2 floats (vs ~6 for the bit-hack pair)
__device__ __forceinline__ unsigned cvt_pk_bf16(float lo, float hi) {
    unsigned r;
    asm("v_cvt_pk_bf16_f32 %0, %1, %2" : "=v"(r) : "v"(lo), "v"(hi));
    return r;
}
__device__ __forceinline__ short8 pack_bf16x8(float4 A, float4 B) {
    uint4v u;
    u[0] = cvt_pk_bf16(A.x, A.y);
    u[1] = cvt_pk_bf16(A.z, A.w);
    u[2] = cvt_pk_bf16(B.x, B.y);
    u[3] = cvt_pk_bf16(B.z, B.w);
    return __builtin_bit_cast(short8, u);
}

// ---- dispatch 1: weight transpose+convert + self-loop preplacement ----
// cnt[d]=1 and srcsP[d*64]=d written here: scatter handles ONLY real edges
// (-50K global atomics vs the ~14 G/s atomic wall) and cnt needs no zeroing.
__global__ void conv_w(const float* __restrict__ Wl1, const float* __restrict__ Wr1,
                       const float* __restrict__ Wl2, const float* __restrict__ Wr2,
                       unsigned short* __restrict__ Wt1, unsigned short* __restrict__ Wt2,
                       int* __restrict__ cnt, unsigned short* __restrict__ srcsP) {
    int idx = blockIdx.x * 256 + threadIdx.x;
    if (idx < N_NODES) {
        cnt[idx] = 1;
        srcsP[idx << 6] = (unsigned short)idx;   // self-loop in slot 0
    }
    if (idx < 512 * 128) {
        int n = idx >> 7, k = idx & 127;
        float v = (n < 256) ? Wl1[(size_t)k * 256 + n] : Wr1[(size_t)k * 256 + (n - 256)];
        Wt1[idx] = f2bf(v);
    } else if (idx < NW) {
        int j = idx - 512 * 128;
        int n = j >> 8, k = j & 255;
        float v = (n < 32) ? Wl2[(size_t)k * 32 + n] : Wr2[(size_t)k * 32 + (n - 32)];
        Wt2[j] = f2bf(v);
    }
}

// ---- FUSED dispatch 2: GEMM1 (MFMA) + bucket scatter (r14 structure) ----
// Scatter: 4 real edges/thread, phase-separated; self-loops preplaced.
// Interleave 2 gemm : 1 scatter across 2346 slots.
__global__ __launch_bounds__(256) void gemm1_scatter(const float* __restrict__ x,
                                                     const unsigned short* __restrict__ Wt1,
                                                     unsigned short* __restrict__ xlh,
                                                     unsigned short* __restrict__ xrh,
                                                     const int* __restrict__ ei,
                                                     int* __restrict__ cnt,
                                                     unsigned short* __restrict__ srcsP) {
    int bid = blockIdx.x;
    int g = bid / 3, r = bid - 3 * g;
    if (r == 2) {
        // ---- scatter: 4 independent real edges per thread ----
        long base = (long)g * 1024 + threadIdx.x;
        int s[4], d[4];
        bool ok[4];
#pragma unroll
        for (int k = 0; k < 4; k++) {
            long e = base + k * 256;
            ok[k] = (e < N_EDGES);
            if (ok[k]) { s[k] = ei[e]; d[k] = ei[N_EDGES + e]; }
        }
        int pos[4];
#pragma unroll
        for (int k = 0; k < 4; k++)
            if (ok[k]) pos[k] = atomicAdd(&cnt[d[k]], 1);
#pragma unroll
        for (int k = 0; k < 4; k++)
            if (ok[k] && pos[k] < CAP)
                __builtin_nontemporal_store((unsigned short)s[k],
                                            &srcsP[(d[k] << 6) + pos[k]]);
        return;
    }
    int wid = 2 * g + r;                 // gemm block id, bijective on [0, 2*SEB)
    if (wid >= G1B) return;              // 1 empty slot, negligible

    // ---- gemm1 body (x->bf16 via v_cvt_pk_bf16_f32; D[feature][node]) ----
    int wave = threadIdx.x >> 6;
    int lane = threadIdx.x & 63;
    int quad = lane >> 4, lo = lane & 15;
    int row0 = wid * 32;
    int colw = wave * 128;
    int rB0 = min(row0 + lo, N_NODES - 1);
    int rB1 = min(row0 + 16 + lo, N_NODES - 1);
    f32x4 acc[2][8];
#pragma unroll
    for (int rt = 0; rt < 2; rt++)
#pragma unroll
        for (int ct = 0; ct < 8; ct++) acc[rt][ct] = (f32x4){0.f, 0.f, 0.f, 0.f};
#pragma unroll
    for (int ks = 0; ks < 4; ks++) {
        int koff = ks * 32 + quad * 8;
        float4 fa0 = *(const float4*)(x + (size_t)rB0 * IN_CH + koff);
        float4 fb0 = *(const float4*)(x + (size_t)rB0 * IN_CH + koff + 4);
        float4 fa1 = *(const float4*)(x + (size_t)rB1 * IN_CH + koff);
        float4 fb1 = *(const float4*)(x + (size_t)rB1 * IN_CH + koff + 4);
        short8 b0 = pack_bf16x8(fa0, fb0);
        short8 b1 = pack_bf16x8(fa1, fb1);
#pragma unroll
        for (int ct = 0; ct < 8; ct++) {
            short8 a = *(const short8*)(Wt1 + (size_t)(colw + ct * 16 + lo) * IN_CH + koff);
            acc[0][ct] = mfma_bf16(a, b0, acc[0][ct]);
            acc[1][ct] = mfma_bf16(a, b1, acc[1][ct]);
        }
    }
#pragma unroll
    for (int rt = 0; rt < 2; rt++) {
        int node = row0 + rt * 16 + lo;
        if (node < N_NODES) {
#pragma unroll
            for (int ct = 0; ct < 8; ct++) {
                int feat = colw + ct * 16 + quad * 4;
                uint2 u;
                u.x = cvt_pk_bf16(acc[rt][ct][0], acc[rt][ct][1]);
                u.y = cvt_pk_bf16(acc[rt][ct][2], acc[rt][ct][3]);
                if (feat < F1)
                    *(uint2*)(xlh + (size_t)node * F1 + feat) = u;
                else
                    *(uint2*)(xrh + (size_t)node * F1 + (feat - F1)) = u;
            }
        }
    }
}

// ------- fused L1: per-dst softmax aggregation + bias + ELU -> hbf (bf16) -------
// Inner loop on REAL v_pk_add_f32 / v_pk_fma_f32 (inline asm; r13's float2 ops
// were likely scalarized -> null). leaky*att = v*(0.6a) + |v|*(0.4a), |v| = 2 ands.
__global__ __launch_bounds__(256) void fused_l1(const unsigned short* __restrict__ xlh,
                                                const unsigned short* __restrict__ xrh,
                                                unsigned short* __restrict__ hbf,
                                                const unsigned short* __restrict__ srcsP,
                                                const int* __restrict__ cnt,
                                                const float* __restrict__ att,
                                                const float* __restrict__ bias) {
    int wave = threadIdx.x >> 6;
    int lane = threadIdx.x & 63;
    int h = lane >> 5;                  // edge parity
    int c = lane & 31;                  // channel-lane: ch c*8 .. c*8+7 (head = c>>3)
    int c0 = c << 3;
    int d = blockIdx.x * 4 + wave;
    if (d >= N_NODES) return;
    uint4v xru = *(const uint4v*)(xrh + (size_t)d * F1 + c0);
    float4 atA = *(const float4*)(att + c0);
    float4 atB = *(const float4*)(att + c0 + 4);
    f32x2 xr2v[4], a6[4], a4[4];
    float at8[8] = {atA.x, atA.y, atA.z, atA.w, atB.x, atB.y, atB.z, atB.w};
#pragma unroll
    for (int p = 0; p < 4; p++) {
        xr2v[p] = up2(xru[p]);
        a6[p] = (f32x2){0.6f * at8[2 * p], 0.6f * at8[2 * p + 1]};
        a4[p] = (f32x2){0.4f * at8[2 * p], 0.4f * at8[2 * p + 1]};
    }
    int start = d << 6;
    int dg    = min(CAP, __builtin_amdgcn_readfirstlane(cnt[d]));
    float l = 0.f;
    f32x2 acc2[4] = {};
    int jj = h;                          // this half's edges: h, h+2, h+4, ...
    int s = srcsP[start + jj];
    uint4v raw = *(const uint4v*)(xlh + (size_t)s * F1 + c0);
    int sN = srcsP[start + jj + 2];
    int iters = (dg + 1) >> 1;
    for (int k = 0; k < iters; k++) {
        uint4v cr = raw;
        raw = *(const uint4v*)(xlh + (size_t)sN * F1 + c0);
        sN = srcsP[start + jj + 4];
        f32x2 ap[4];
        f32x2 sp = (f32x2){0.f, 0.f};
#pragma unroll
        for (int p = 0; p < 4; p++) {
            ap[p] = up2(cr[p]);
            f32x2 v = pk_add(ap[p], xr2v[p]);        // v_pk_add_f32
            sp = pk_fma(v, a6[p], sp);               // v_pk_fma_f32
            sp = pk_fma(abs2(v), a4[p], sp);         // |v| = 2 v_and + pk_fma
        }
        float sc = sp[0] + sp[1];
        sc += __shfl_xor(sc, 1);
        sc += __shfl_xor(sc, 2);
        sc += __shfl_xor(sc, 4);
        float ex = (jj < dg) ? __expf(sc) : 0.f;
        l += ex;
        f32x2 ex2 = (f32x2){ex, ex};
#pragma unroll
        for (int p = 0; p < 4; p++) acc2[p] = pk_fma(ex2, ap[p], acc2[p]);
        jj += 2;
    }
    float acc[8];
#pragma unroll
    for (int p = 0; p < 4; p++) { acc[2 * p] = acc2[p][0]; acc[2 * p + 1] = acc2[p][1]; }
    l += __shfl_xor(l, 32);
#pragma unroll
    for (int i = 0; i < 8; i++) acc[i] += __shfl_xor(acc[i], 32);
    if (h == 0) {
        float inv = 1.0f / l;
        float4 bA = *(const float4*)(bias + c0);
        float4 bB = *(const float4*)(bias + c0 + 4);
        float b8[8] = {bA.x, bA.y, bA.z, bA.w, bB.x, bB.y, bB.z, bB.w};
        ushort8v ho;
#pragma unroll
        for (int i = 0; i < 8; i++) {
            float o = acc[i] * inv + b8[i];
            o = o > 0.f ? o : __expf(o) - 1.0f;
            ho[i] = (unsigned short)f2bf(o);
        }
        *(ushort8v*)(hbf + (size_t)d * F1 + c0) = ho;
    }
}

// ---- GEMM2 (MFMA, swapped operands): hbf(N,256) @ Wt2^T -> xl2h fp16 / xr2 fp32 ----
__global__ __launch_bounds__(256) void gemm2_mfma(const unsigned short* __restrict__ hbf,
                                                  const unsigned short* __restrict__ Wt2,
                                                  __half* __restrict__ xl2h,
                                                  float* __restrict__ xr2) {
    int wave = threadIdx.x >> 6;
    int lane = threadIdx.x & 63;
    int quad = lane >> 4, lo = lane & 15;
    int row0 = blockIdx.x * 64 + wave * 16;
    int rB = min(row0 + lo, N_NODES - 1);
    f32x4 acc[4];
#pragma unroll
    for (int ct = 0; ct < 4; ct++) acc[ct] = (f32x4){0.f, 0.f, 0.f, 0.f};
#pragma unroll
    for (int ks = 0; ks < 8; ks++) {
        int koff = ks * 32 + quad * 8;
        short8 b = *(const short8*)(hbf + (size_t)rB * F1 + koff);
#pragma unroll
        for (int ct = 0; ct < 4; ct++) {
            short8 a = *(const short8*)(Wt2 + (size_t)(ct * 16 + lo) * F1 + koff);
            acc[ct] = mfma_bf16(a, b, acc[ct]);
        }
    }
    int node = row0 + lo;
    if (node < N_NODES) {
#pragma unroll
        for (int ct = 0; ct < 4; ct++) {
            int feat = ct * 16 + quad * 4;
            if (feat < LAT) {
                ushort4 u;
                u.x = __half_as_ushort(__float2half_rn(acc[ct][0]));
                u.y = __half_as_ushort(__float2half_rn(acc[ct][1]));
                u.z = __half_as_ushort(__float2half_rn(acc[ct][2]));
                u.w = __half_as_ushort(__float2half_rn(acc[ct][3]));
                *(ushort4*)((unsigned short*)xl2h + (size_t)node * LAT + feat) = u;
            } else {
                float4 f = make_float4(acc[ct][0], acc[ct][1], acc[ct][2], acc[ct][3]);
                *(float4*)(xr2 + (size_t)node * LAT + (feat - LAT)) = f;
            }
        }
    }
}

// ------- fused L2: one dst per wave; quarter-wave per edge, bucket layout -------
__global__ __launch_bounds__(256) void fused_l2(const __half* __restrict__ xl2h,
                                                const float* __restrict__ xr2,
                                                const unsigned short* __restrict__ srcsP,
                                                const int* __restrict__ cnt,
                                                const float* __restrict__ att,
                                                const float* __restrict__ bias,
                                                __half* __restrict__ zh) {
    int wave = threadIdx.x >> 6;
    int lane = threadIdx.x & 63;
    int q = lane >> 4;                  // edge parity class 0..3
    int c = lane & 15;                  // channel-lane: ch 2c, 2c+1
    int c2 = c << 1;
    int d = blockIdx.x * 4 + wave;
    if (d >= N_NODES) return;
    float xr0 = xr2[(size_t)d * LAT + c2];
    float xr1v = xr2[(size_t)d * LAT + c2 + 1];
    float av0 = att[c2], av1 = att[c2 + 1];
    float a60 = 0.6f * av0, a40 = 0.4f * av0;
    float a61 = 0.6f * av1, a41 = 0.4f * av1;
    int start = d << 6;
    int dg    = min(CAP, __builtin_amdgcn_readfirstlane(cnt[d]));
    float l = 0.f, acc0 = 0.f, acc1 = 0.f;
    int jj = q;                         // this quarter's edges: q, q+4, q+8, ...
    int s = srcsP[start + jj];
    __half2 raw = *(const __half2*)(xl2h + (size_t)s * LAT + c2);
    int sN = srcsP[start + jj + 4];
    int iters = (dg + 3) >> 2;
    for (int k = 0; k < iters; k++) {
        __half2 cr = raw;
        raw = *(const __half2*)(xl2h + (size_t)sN * LAT + c2);
        sN = srcsP[start + jj + 8];
        float a0 = __half2float(cr.x), a1 = __half2float(cr.y);
        float v0 = a0 + xr0;
        float v1 = a1 + xr1v;
        float sc = 0.f;
        sc = fmaf(v0, a60, sc);
        sc = fmaf(fabsf(v0), a40, sc);
        sc = fmaf(v1, a61, sc);
        sc = fmaf(fabsf(v1), a41, sc);
        sc += __shfl_xor(sc, 1);
        sc += __shfl_xor(sc, 2);
        sc += __shfl_xor(sc, 4);
        sc += __shfl_xor(sc, 8);
        float ex = (jj < dg) ? __expf(sc) : 0.f;
        l += ex;
        acc0 = fmaf(ex, a0, acc0);
        acc1 = fmaf(ex, a1, acc1);
        jj += 4;
    }
    l += __shfl_xor(l, 16); acc0 += __shfl_xor(acc0, 16); acc1 += __shfl_xor(acc1, 16);
    l += __shfl_xor(l, 32); acc0 += __shfl_xor(acc0, 32); acc1 += __shfl_xor(acc1, 32);
    if (q == 0) {
        __half2 o;
        o.x = __float2half_rn(acc0 / l + bias[c2]);
        o.y = __float2half_rn(acc1 / l + bias[c2 + 1]);
        *(__half2*)(zh + (size_t)d * LAT + c2) = o;
    }
}

// ------- decode: sigmoid(<z[row], z[col]>), z fp16, 4 lanes/edge, 16B loads ----
__global__ __launch_bounds__(256) void decode(const __half* __restrict__ zh,
                                              const int* __restrict__ ei,
                                              float* __restrict__ out) {
    int g = threadIdx.x >> 2;             // 64 edge-groups per block
    int lane = threadIdx.x & 3;
    long e = (long)blockIdx.x * 64 + g;
    if (e >= N_EDGES) return;
    int r = ei[e], c = ei[N_EDGES + e];
    int cc = lane << 3;                   // 8 channels
    ushort8v ur = *(const ushort8v*)((const unsigned short*)zh + (size_t)r * LAT + cc);
    ushort8v uc = *(const ushort8v*)((const unsigned short*)zh + (size_t)c * LAT + cc);
    float v = 0.f;
#pragma unroll
    for (int i = 0; i < 8; i++) {
        v += h2f(ur[i]) * h2f(uc[i]);
    }
    v += __shfl_xor(v, 1);
    v += __shfl_xor(v, 2);
    if (lane == 0) out[e] = 1.0f / (1.0f + __expf(-v));
}

extern "C" void kernel_launch(void* const* d_in, const int* in_sizes, int n_in,
                              void* d_out, int out_size, void* d_ws, size_t ws_size,
                              hipStream_t stream) {
    const float* x    = (const float*)d_in[0];
    const int*   ei   = (const int*)d_in[1];
    const float* Wl1  = (const float*)d_in[2];
    const float* Wr1  = (const float*)d_in[3];
    const float* att1 = (const float*)d_in[4];
    const float* b1   = (const float*)d_in[5];
    const float* Wl2  = (const float*)d_in[6];
    const float* Wr2  = (const float*)d_in[7];
    const float* att2 = (const float*)d_in[8];
    const float* b2   = (const float*)d_in[9];
    float* out = (float*)d_out;

    unsigned short* xrh = (unsigned short*)d_ws;                 // N*256 bf16 (25.6 MB)
    unsigned short* hbf = xrh + (size_t)N_NODES * F1;            // N*256 bf16 (25.6 MB)
    unsigned short* xlh = hbf + (size_t)N_NODES * F1;            // N*256 bf16 (25.6 MB)
    int* cnt = (int*)(xlh + (size_t)N_NODES * F1);               // N ints (16B-aligned)
    unsigned short* srcsP = (unsigned short*)(cnt + N_NODES);    // N*64+16 ushorts (6.4 MB)
    unsigned short* Wt1 = srcsP + (size_t)N_NODES * CAP + 16;    // 512*128 bf16
    unsigned short* Wt2 = Wt1 + 512 * 128;                       // 64*256 bf16
    // layer-2 buffers reuse the xlh region (dead after fused_l1): 12.8 MB
    __half* xl2h = (__half*)xlh;                                 // N*32 fp16
    float*  xr2  = (float*)(xl2h + (size_t)N_NODES * LAT);
    __half* zh   = (__half*)(xr2 + (size_t)N_NODES * LAT);

    // ---- 1: weights bf16 + cnt=1 + self-loop preplacement ----
    conv_w<<<(NW + 255) / 256, 256, 0, stream>>>(Wl1, Wr1, Wl2, Wr2, Wt1, Wt2,
                                                 cnt, srcsP);

    // ---- 2: FUSED layer-1 GEMM + bucket scatter (real edges only, 2:1 mix) ----
    gemm1_scatter<<<TB, 256, 0, stream>>>(x, Wt1, xlh, xrh, ei, cnt, srcsP);

    // ---- 3: layer 1 aggregate (true packed-f32 via inline asm) ----
    fused_l1<<<(N_NODES + 3) / 4, 256, 0, stream>>>(xlh, xrh, hbf, srcsP, cnt, att1, b1);

    // ---- 4/5: layer 2 ----
    gemm2_mfma<<<(N_NODES + 63) / 64, 256, 0, stream>>>(hbf, Wt2, xl2h, xr2);
    fused_l2<<<(N_NODES + 3) / 4, 256, 0, stream>>>(xl2h, xr2, srcsP, cnt, att2, b2, zh);

    // ---- 6: decode ----
    decode<<<(N_EDGES + 63) / 64, 256, 0, stream>>>(zh, ei, out);
}

// Round 17
// 282.387 us; speedup vs baseline: 3.4260x; 1.0184x over previous
//
#include <hip/hip_runtime.h>
#include <hip/hip_fp16.h>
#include <math.h>

#define N_NODES 50000
#define N_EDGES 800000
#define IN_CH 128
#define HID 64
#define HEADS 4
#define F1 (HEADS * HID)         /* 256 */
#define LAT 32
#define NEG 0.2f
#define CAP 64                    /* bucket capacity per dst; P(overflow) ~1e-13 */
#define NW (512 * 128 + 64 * 256) /* weight elements: 81920 */
#define G1B ((N_NODES + 31) / 32)       /* 1563 gemm1 blocks */
#define SEB ((N_EDGES + 1023) / 1024)   /* 782 scatter blocks (4 edges/thread) */
#define TB (3 * SEB)                    /* 2346 fused-grid slots (2 gemm : 1 scatter) */

typedef __attribute__((ext_vector_type(8))) short short8;
typedef __attribute__((ext_vector_type(8))) unsigned short ushort8v;
typedef __attribute__((ext_vector_type(4))) float f32x4;
typedef __attribute__((ext_vector_type(2))) float f32x2;
typedef __attribute__((ext_vector_type(4))) unsigned int uint4v;

__device__ __forceinline__ unsigned short f2bf(float f) {
    unsigned int x = __float_as_uint(f);
    x += 0x7fffu + ((x >> 16) & 1u);       // round-to-nearest-even
    return (unsigned short)(x >> 16);
}
__device__ __forceinline__ float bf2f(unsigned short u) {
    return __uint_as_float(((unsigned int)u) << 16);
}
__device__ __forceinline__ float h2f(unsigned short u) {
    return __half2float(__ushort_as_half(u));
}
// unpack 2 bf16 (packed in a u32) -> float2; 2 VALU (lshl, and)
__device__ __forceinline__ f32x2 up2(unsigned w) {
    f32x2 r;
    r[0] = __uint_as_float(w << 16);
    r[1] = __uint_as_float(w & 0xffff0000u);
    return r;
}
__device__ __forceinline__ f32x4 mfma_bf16(short8 a, short8 b, f32x4 c) {
    return __builtin_amdgcn_mfma_f32_16x16x32_bf16(a, b, c, 0, 0, 0);
}
// packed f32->bf16 RNE: 1 instr per 2 floats (vs ~6 for the bit-hack pair)
__device__ __forceinline__ unsigned cvt_pk_bf16(float lo, float hi) {
    unsigned r;
    asm("v_cvt_pk_bf16_f32 %0, %1, %2" : "=v"(r) : "v"(lo), "v"(hi));
    return r;
}
__device__ __forceinline__ short8 pack_bf16x8(float4 A, float4 B) {
    uint4v u;
    u[0] = cvt_pk_bf16(A.x, A.y);
    u[1] = cvt_pk_bf16(A.z, A.w);
    u[2] = cvt_pk_bf16(B.x, B.y);
    u[3] = cvt_pk_bf16(B.z, B.w);
    return __builtin_bit_cast(short8, u);
}

// ---- dispatch 1: weight transpose+convert + self-loop preplacement ----
// cnt[d]=1 and srcsP[d*64]=d written here: scatter handles ONLY real edges
// (-50K global atomics vs the ~14 G/s atomic wall) and cnt needs no zeroing.
__global__ void conv_w(const float* __restrict__ Wl1, const float* __restrict__ Wr1,
                       const float* __restrict__ Wl2, const float* __restrict__ Wr2,
                       unsigned short* __restrict__ Wt1, unsigned short* __restrict__ Wt2,
                       int* __restrict__ cnt, unsigned short* __restrict__ srcsP) {
    int idx = blockIdx.x * 256 + threadIdx.x;
    if (idx < N_NODES) {
        cnt[idx] = 1;
        srcsP[idx << 6] = (unsigned short)idx;   // self-loop in slot 0
    }
    if (idx < 512 * 128) {
        int n = idx >> 7, k = idx & 127;
        float v = (n < 256) ? Wl1[(size_t)k * 256 + n] : Wr1[(size_t)k * 256 + (n - 256)];
        Wt1[idx] = f2bf(v);
    } else if (idx < NW) {
        int j = idx - 512 * 128;
        int n = j >> 8, k = j & 255;
        float v = (n < 32) ? Wl2[(size_t)k * 32 + n] : Wr2[(size_t)k * 32 + (n - 32)];
        Wt2[j] = f2bf(v);
    }
}

// ---- FUSED dispatch 2: GEMM1 (MFMA) + bucket scatter (r14 structure) ----
// Scatter: 4 real edges/thread, phase-separated; self-loops preplaced.
// Interleave 2 gemm : 1 scatter across 2346 slots.
__global__ __launch_bounds__(256) void gemm1_scatter(const float* __restrict__ x,
                                                     const unsigned short* __restrict__ Wt1,
                                                     unsigned short* __restrict__ xlh,
                                                     unsigned short* __restrict__ xrh,
                                                     const int* __restrict__ ei,
                                                     int* __restrict__ cnt,
                                                     unsigned short* __restrict__ srcsP) {
    int bid = blockIdx.x;
    int g = bid / 3, r = bid - 3 * g;
    if (r == 2) {
        // ---- scatter: 4 independent real edges per thread ----
        long base = (long)g * 1024 + threadIdx.x;
        int s[4], d[4];
        bool ok[4];
#pragma unroll
        for (int k = 0; k < 4; k++) {
            long e = base + k * 256;
            ok[k] = (e < N_EDGES);
            if (ok[k]) { s[k] = ei[e]; d[k] = ei[N_EDGES + e]; }
        }
        int pos[4];
#pragma unroll
        for (int k = 0; k < 4; k++)
            if (ok[k]) pos[k] = atomicAdd(&cnt[d[k]], 1);
#pragma unroll
        for (int k = 0; k < 4; k++)
            if (ok[k] && pos[k] < CAP)
                __builtin_nontemporal_store((unsigned short)s[k],
                                            &srcsP[(d[k] << 6) + pos[k]]);
        return;
    }
    int wid = 2 * g + r;                 // gemm block id, bijective on [0, 2*SEB)
    if (wid >= G1B) return;              // 1 empty slot, negligible

    // ---- gemm1 body (x->bf16 via v_cvt_pk_bf16_f32; D[feature][node]) ----
    int wave = threadIdx.x >> 6;
    int lane = threadIdx.x & 63;
    int quad = lane >> 4, lo = lane & 15;
    int row0 = wid * 32;
    int colw = wave * 128;
    int rB0 = min(row0 + lo, N_NODES - 1);
    int rB1 = min(row0 + 16 + lo, N_NODES - 1);
    f32x4 acc[2][8];
#pragma unroll
    for (int rt = 0; rt < 2; rt++)
#pragma unroll
        for (int ct = 0; ct < 8; ct++) acc[rt][ct] = (f32x4){0.f, 0.f, 0.f, 0.f};
#pragma unroll
    for (int ks = 0; ks < 4; ks++) {
        int koff = ks * 32 + quad * 8;
        float4 fa0 = *(const float4*)(x + (size_t)rB0 * IN_CH + koff);
        float4 fb0 = *(const float4*)(x + (size_t)rB0 * IN_CH + koff + 4);
        float4 fa1 = *(const float4*)(x + (size_t)rB1 * IN_CH + koff);
        float4 fb1 = *(const float4*)(x + (size_t)rB1 * IN_CH + koff + 4);
        short8 b0 = pack_bf16x8(fa0, fb0);
        short8 b1 = pack_bf16x8(fa1, fb1);
#pragma unroll
        for (int ct = 0; ct < 8; ct++) {
            short8 a = *(const short8*)(Wt1 + (size_t)(colw + ct * 16 + lo) * IN_CH + koff);
            acc[0][ct] = mfma_bf16(a, b0, acc[0][ct]);
            acc[1][ct] = mfma_bf16(a, b1, acc[1][ct]);
        }
    }
#pragma unroll
    for (int rt = 0; rt < 2; rt++) {
        int node = row0 + rt * 16 + lo;
        if (node < N_NODES) {
#pragma unroll
            for (int ct = 0; ct < 8; ct++) {
                int feat = colw + ct * 16 + quad * 4;
                uint2 u;
                u.x = cvt_pk_bf16(acc[rt][ct][0], acc[rt][ct][1]);
                u.y = cvt_pk_bf16(acc[rt][ct][2], acc[rt][ct][3]);
                if (feat < F1)
                    *(uint2*)(xlh + (size_t)node * F1 + feat) = u;
                else
                    *(uint2*)(xrh + (size_t)node * F1 + (feat - F1)) = u;
            }
        }
    }
}

// ------- fused L1: per-dst softmax aggregation + bias + ELU -> hbf (bf16) -------
// r13 float2 formulation (compiler-scheduled; the asm-VOP3P variant regressed
// 65->76us in r16 — compiler's scalar/packed choice is already optimal here).
__global__ __launch_bounds__(256) void fused_l1(const unsigned short* __restrict__ xlh,
                                                const unsigned short* __restrict__ xrh,
                                                unsigned short* __restrict__ hbf,
                                                const unsigned short* __restrict__ srcsP,
                                                const int* __restrict__ cnt,
                                                const float* __restrict__ att,
                                                const float* __restrict__ bias) {
    int wave = threadIdx.x >> 6;
    int lane = threadIdx.x & 63;
    int h = lane >> 5;                  // edge parity
    int c = lane & 31;                  // channel-lane: ch c*8 .. c*8+7 (head = c>>3)
    int c0 = c << 3;
    int d = blockIdx.x * 4 + wave;
    if (d >= N_NODES) return;
    uint4v xru = *(const uint4v*)(xrh + (size_t)d * F1 + c0);
    float4 atA = *(const float4*)(att + c0);
    float4 atB = *(const float4*)(att + c0 + 4);
    f32x2 xr2v[4], at2[4];
#pragma unroll
    for (int p = 0; p < 4; p++) xr2v[p] = up2(xru[p]);
    at2[0] = (f32x2){atA.x, atA.y};
    at2[1] = (f32x2){atA.z, atA.w};
    at2[2] = (f32x2){atB.x, atB.y};
    at2[3] = (f32x2){atB.z, atB.w};
    const f32x2 negv = (f32x2){NEG, NEG};
    int start = d << 6;
    int dg    = min(CAP, __builtin_amdgcn_readfirstlane(cnt[d]));
    float l = 0.f;
    f32x2 acc2[4] = {};
    int jj = h;                          // this half's edges: h, h+2, h+4, ...
    int s = srcsP[start + jj];
    uint4v raw = *(const uint4v*)(xlh + (size_t)s * F1 + c0);
    int sN = srcsP[start + jj + 2];
    int iters = (dg + 1) >> 1;
    for (int k = 0; k < iters; k++) {
        uint4v cr = raw;
        raw = *(const uint4v*)(xlh + (size_t)sN * F1 + c0);
        sN = srcsP[start + jj + 4];
        f32x2 ap[4];
        f32x2 sp = (f32x2){0.f, 0.f};
#pragma unroll
        for (int p = 0; p < 4; p++) {
            ap[p] = up2(cr[p]);
            f32x2 v = ap[p] + xr2v[p];                       // v_pk_add_f32
            f32x2 lk = __builtin_elementwise_max(v, v * negv); // pk_mul + pk_max
            sp = lk * at2[p] + sp;                           // v_pk_fma_f32
        }
        float sc = sp[0] + sp[1];
        sc += __shfl_xor(sc, 1);
        sc += __shfl_xor(sc, 2);
        sc += __shfl_xor(sc, 4);
        float ex = (jj < dg) ? __expf(sc) : 0.f;
        l += ex;
        f32x2 ex2 = (f32x2){ex, ex};
#pragma unroll
        for (int p = 0; p < 4; p++) acc2[p] = ex2 * ap[p] + acc2[p]; // pk_fma
        jj += 2;
    }
    float acc[8];
#pragma unroll
    for (int p = 0; p < 4; p++) { acc[2 * p] = acc2[p][0]; acc[2 * p + 1] = acc2[p][1]; }
    l += __shfl_xor(l, 32);
#pragma unroll
    for (int i = 0; i < 8; i++) acc[i] += __shfl_xor(acc[i], 32);
    if (h == 0) {
        float inv = 1.0f / l;
        float4 bA = *(const float4*)(bias + c0);
        float4 bB = *(const float4*)(bias + c0 + 4);
        float b8[8] = {bA.x, bA.y, bA.z, bA.w, bB.x, bB.y, bB.z, bB.w};
        ushort8v ho;
#pragma unroll
        for (int i = 0; i < 8; i++) {
            float o = acc[i] * inv + b8[i];
            o = o > 0.f ? o : __expf(o) - 1.0f;
            ho[i] = (unsigned short)f2bf(o);
        }
        *(ushort8v*)(hbf + (size_t)d * F1 + c0) = ho;
    }
}

// ---- GEMM2 (MFMA, swapped operands): hbf(N,256) @ Wt2^T -> xl2h fp16 / xr2 fp32 ----
__global__ __launch_bounds__(256) void gemm2_mfma(const unsigned short* __restrict__ hbf,
                                                  const unsigned short* __restrict__ Wt2,
                                                  __half* __restrict__ xl2h,
                                                  float* __restrict__ xr2) {
    int wave = threadIdx.x >> 6;
    int lane = threadIdx.x & 63;
    int quad = lane >> 4, lo = lane & 15;
    int row0 = blockIdx.x * 64 + wave * 16;
    int rB = min(row0 + lo, N_NODES - 1);
    f32x4 acc[4];
#pragma unroll
    for (int ct = 0; ct < 4; ct++) acc[ct] = (f32x4){0.f, 0.f, 0.f, 0.f};
#pragma unroll
    for (int ks = 0; ks < 8; ks++) {
        int koff = ks * 32 + quad * 8;
        short8 b = *(const short8*)(hbf + (size_t)rB * F1 + koff);
#pragma unroll
        for (int ct = 0; ct < 4; ct++) {
            short8 a = *(const short8*)(Wt2 + (size_t)(ct * 16 + lo) * F1 + koff);
            acc[ct] = mfma_bf16(a, b, acc[ct]);
        }
    }
    int node = row0 + lo;
    if (node < N_NODES) {
#pragma unroll
        for (int ct = 0; ct < 4; ct++) {
            int feat = ct * 16 + quad * 4;
            if (feat < LAT) {
                ushort4 u;
                u.x = __half_as_ushort(__float2half_rn(acc[ct][0]));
                u.y = __half_as_ushort(__float2half_rn(acc[ct][1]));
                u.z = __half_as_ushort(__float2half_rn(acc[ct][2]));
                u.w = __half_as_ushort(__float2half_rn(acc[ct][3]));
                *(ushort4*)((unsigned short*)xl2h + (size_t)node * LAT + feat) = u;
            } else {
                float4 f = make_float4(acc[ct][0], acc[ct][1], acc[ct][2], acc[ct][3]);
                *(float4*)(xr2 + (size_t)node * LAT + (feat - LAT)) = f;
            }
        }
    }
}

// ------- fused L2: one dst per wave; quarter-wave per edge, bucket layout -------
__global__ __launch_bounds__(256) void fused_l2(const __half* __restrict__ xl2h,
                                                const float* __restrict__ xr2,
                                                const unsigned short* __restrict__ srcsP,
                                                const int* __restrict__ cnt,
                                                const float* __restrict__ att,
                                                const float* __restrict__ bias,
                                                __half* __restrict__ zh) {
    int wave = threadIdx.x >> 6;
    int lane = threadIdx.x & 63;
    int q = lane >> 4;                  // edge parity class 0..3
    int c = lane & 15;                  // channel-lane: ch 2c, 2c+1
    int c2 = c << 1;
    int d = blockIdx.x * 4 + wave;
    if (d >= N_NODES) return;
    float xr0 = xr2[(size_t)d * LAT + c2];
    float xr1v = xr2[(size_t)d * LAT + c2 + 1];
    float av0 = att[c2], av1 = att[c2 + 1];
    float a60 = 0.6f * av0, a40 = 0.4f * av0;
    float a61 = 0.6f * av1, a41 = 0.4f * av1;
    int start = d << 6;
    int dg    = min(CAP, __builtin_amdgcn_readfirstlane(cnt[d]));
    float l = 0.f, acc0 = 0.f, acc1 = 0.f;
    int jj = q;                         // this quarter's edges: q, q+4, q+8, ...
    int s = srcsP[start + jj];
    __half2 raw = *(const __half2*)(xl2h + (size_t)s * LAT + c2);
    int sN = srcsP[start + jj + 4];
    int iters = (dg + 3) >> 2;
    for (int k = 0; k < iters; k++) {
        __half2 cr = raw;
        raw = *(const __half2*)(xl2h + (size_t)sN * LAT + c2);
        sN = srcsP[start + jj + 8];
        float a0 = __half2float(cr.x), a1 = __half2float(cr.y);
        float v0 = a0 + xr0;
        float v1 = a1 + xr1v;
        float sc = 0.f;
        sc = fmaf(v0, a60, sc);
        sc = fmaf(fabsf(v0), a40, sc);
        sc = fmaf(v1, a61, sc);
        sc = fmaf(fabsf(v1), a41, sc);
        sc += __shfl_xor(sc, 1);
        sc += __shfl_xor(sc, 2);
        sc += __shfl_xor(sc, 4);
        sc += __shfl_xor(sc, 8);
        float ex = (jj < dg) ? __expf(sc) : 0.f;
        l += ex;
        acc0 = fmaf(ex, a0, acc0);
        acc1 = fmaf(ex, a1, acc1);
        jj += 4;
    }
    l += __shfl_xor(l, 16); acc0 += __shfl_xor(acc0, 16); acc1 += __shfl_xor(acc1, 16);
    l += __shfl_xor(l, 32); acc0 += __shfl_xor(acc0, 32); acc1 += __shfl_xor(acc1, 32);
    if (q == 0) {
        __half2 o;
        o.x = __float2half_rn(acc0 / l + bias[c2]);
        o.y = __float2half_rn(acc1 / l + bias[c2 + 1]);
        *(__half2*)(zh + (size_t)d * LAT + c2) = o;
    }
}

// ------- decode: sigmoid(<z[row], z[col]>), z fp16, 4 lanes/edge, 16B loads ----
__global__ __launch_bounds__(256) void decode(const __half* __restrict__ zh,
                                              const int* __restrict__ ei,
                                              float* __restrict__ out) {
    int g = threadIdx.x >> 2;             // 64 edge-groups per block
    int lane = threadIdx.x & 3;
    long e = (long)blockIdx.x * 64 + g;
    if (e >= N_EDGES) return;
    int r = ei[e], c = ei[N_EDGES + e];
    int cc = lane << 3;                   // 8 channels
    ushort8v ur = *(const ushort8v*)((const unsigned short*)zh + (size_t)r * LAT + cc);
    ushort8v uc = *(const ushort8v*)((const unsigned short*)zh + (size_t)c * LAT + cc);
    float v = 0.f;
#pragma unroll
    for (int i = 0; i < 8; i++) {
        v += h2f(ur[i]) * h2f(uc[i]);
    }
    v += __shfl_xor(v, 1);
    v += __shfl_xor(v, 2);
    if (lane == 0) out[e] = 1.0f / (1.0f + __expf(-v));
}

extern "C" void kernel_launch(void* const* d_in, const int* in_sizes, int n_in,
                              void* d_out, int out_size, void* d_ws, size_t ws_size,
                              hipStream_t stream) {
    const float* x    = (const float*)d_in[0];
    const int*   ei   = (const int*)d_in[1];
    const float* Wl1  = (const float*)d_in[2];
    const float* Wr1  = (const float*)d_in[3];
    const float* att1 = (const float*)d_in[4];
    const float* b1   = (const float*)d_in[5];
    const float* Wl2  = (const float*)d_in[6];
    const float* Wr2  = (const float*)d_in[7];
    const float* att2 = (const float*)d_in[8];
    const float* b2   = (const float*)d_in[9];
    float* out = (float*)d_out;

    unsigned short* xrh = (unsigned short*)d_ws;                 // N*256 bf16 (25.6 MB)
    unsigned short* hbf = xrh + (size_t)N_NODES * F1;            // N*256 bf16 (25.6 MB)
    unsigned short* xlh = hbf + (size_t)N_NODES * F1;            // N*256 bf16 (25.6 MB)
    int* cnt = (int*)(xlh + (size_t)N_NODES * F1);               // N ints (16B-aligned)
    unsigned short* srcsP = (unsigned short*)(cnt + N_NODES);    // N*64+16 ushorts (6.4 MB)
    unsigned short* Wt1 = srcsP + (size_t)N_NODES * CAP + 16;    // 512*128 bf16
    unsigned short* Wt2 = Wt1 + 512 * 128;                       // 64*256 bf16
    // layer-2 buffers reuse the xlh region (dead after fused_l1): 12.8 MB
    __half* xl2h = (__half*)xlh;                                 // N*32 fp16
    float*  xr2  = (float*)(xl2h + (size_t)N_NODES * LAT);
    __half* zh   = (__half*)(xr2 + (size_t)N_NODES * LAT);

    // ---- 1: weights bf16 + cnt=1 + self-loop preplacement ----
    conv_w<<<(NW + 255) / 256, 256, 0, stream>>>(Wl1, Wr1, Wl2, Wr2, Wt1, Wt2,
                                                 cnt, srcsP);

    // ---- 2: FUSED layer-1 GEMM + bucket scatter (real edges only, 2:1 mix) ----
    gemm1_scatter<<<TB, 256, 0, stream>>>(x, Wt1, xlh, xrh, ei, cnt, srcsP);

    // ---- 3: layer 1 aggregate (r13 float2 math) ----
    fused_l1<<<(N_NODES + 3) / 4, 256, 0, stream>>>(xlh, xrh, hbf, srcsP, cnt, att1, b1);

    // ---- 4/5: layer 2 ----
    gemm2_mfma<<<(N_NODES + 63) / 64, 256, 0, stream>>>(hbf, Wt2, xl2h, xr2);
    fused_l2<<<(N_NODES + 3) / 4, 256, 0, stream>>>(xl2h, xr2, srcsP, cnt, att2, b2, zh);

    // ---- 6: decode ----
    decode<<<(N_EDGES + 63) / 64, 256, 0, stream>>>(zh, ei, out);
}